// Round 2
// 147.793 us; speedup vs baseline: 1.0494x; 1.0494x over previous
//
#include <hip/hip_runtime.h>
#include <hip/hip_bf16.h>

// WaveletBlock fused kernel (f32 in/out): DWT -> GEMM1(+bias,SiLU) -> GEMM2(+bias) -> IDWT
// R5: differential split of R4. Verbatim R3 math (phase-1 mapping, DWT formulas, GEMM
// fragments, LDS-y + phase-4 IDWT epilogue, unpermuted cvt_w) + ONLY the 2-row pipeline:
//   - grid 512, rows (bid, bid+512) per block.
//   - phase-1 split into load_st (pure global loads into 64 VGPRs) / dwt_write (math+LDS).
//   - row-1 loads issued right after the first barrier (T14 issue-early/consume-late):
//     their HBM latency drains under row-0's two K=256 GEMMs, de-bursting the
//     [all-load][all-compute][all-store] lockstep seen in R3's counters.
//   - launch_bounds(256,2): VGPR cap 256 for the staged regs; 2 blocks/CU, all 512
//     blocks co-resident.

typedef __bf16 bf16x8 __attribute__((ext_vector_type(8)));
typedef float  f32x4  __attribute__((ext_vector_type(4)));

#define SP 264  // LDS row stride in bf16 elems: 528 B = 132 dwords == 4 mod 32 banks;
                // rows stay 16B-aligned for ds_read_b128. GEMM-phase accesses are <=2-way.

__device__ __forceinline__ unsigned short f2bf(float f) {
  __hip_bfloat16 h = __float2bfloat16(f);
  return __builtin_bit_cast(unsigned short, h);
}
__device__ __forceinline__ float bf2f(unsigned short s) {
  union { unsigned int i; float f; } v; v.i = ((unsigned int)s) << 16; return v.f;
}
__device__ __forceinline__ float silu(float f) {
  return f / (1.0f + __expf(-f));
}
// Load 8 consecutive f32 weights, convert to a bf16x8 MFMA fragment (fallback path).
__device__ __forceinline__ bf16x8 ldw8(const float* __restrict__ p) {
  const float4 a = *(const float4*)p;
  const float4 b = *(const float4*)(p + 4);
  bf16x8 r;
  r[0] = (__bf16)a.x; r[1] = (__bf16)a.y; r[2] = (__bf16)a.z; r[3] = (__bf16)a.w;
  r[4] = (__bf16)b.x; r[5] = (__bf16)b.y; r[6] = (__bf16)b.z; r[7] = (__bf16)b.w;
  return r;
}

// Prelude: f32 -> bf16 weight conversion into workspace (verbatim R3, no permutation).
__global__ __launch_bounds__(256) void cvt_w(const float* __restrict__ w1,
                                             const float* __restrict__ w2,
                                             unsigned short* __restrict__ o) {
  const int i = (blockIdx.x * 256 + threadIdx.x) * 4;  // grid 64 x 256 covers 65536
  const float4 a = *(const float4*)(w1 + i);
  const float4 b = *(const float4*)(w2 + i);
  *(ushort4*)(o + i)         = make_ushort4(f2bf(a.x), f2bf(a.y), f2bf(a.z), f2bf(a.w));
  *(ushort4*)(o + 65536 + i) = make_ushort4(f2bf(b.x), f2bf(b.y), f2bf(b.z), f2bf(b.w));
}

// Phase-1a: issue one row's x loads into registers (R3's exact mapping: thread t handles
// pixel ww = t&63, channel groups cg = t>>6; 32x float2 = 64 VGPRs).
__device__ __forceinline__ void load_st(const float* __restrict__ x, int n, int hh,
                                        int ww, int cg, float2 (&st)[32]) {
  const float* xb = x + ((size_t)n * 64 * 128 + (size_t)(2 * hh)) * 128 + 2 * ww;
  #pragma unroll
  for (int j = 0; j < 4; ++j) {
    const int c0 = (cg + 4 * j) * 4;
    #pragma unroll
    for (int ci = 0; ci < 4; ++ci) {
      const float* p = xb + (size_t)(c0 + ci) * (128 * 128);
      st[(j * 4 + ci) * 2]     = *(const float2*)p;          // x[2hh,   2ww], x[2hh,   2ww+1]
      st[(j * 4 + ci) * 2 + 1] = *(const float2*)(p + 128);  // x[2hh+1, 2ww], x[2hh+1, 2ww+1]
    }
  }
}

// Phase-1b: Haar DWT of staged regs -> lds[ww][q*64+c] as bf16 (verbatim R3 math/writes).
__device__ __forceinline__ void dwt_write(const float2 (&st)[32], unsigned short* lds,
                                          int ww, int cg) {
  #pragma unroll
  for (int j = 0; j < 4; ++j) {
    const int c0 = (cg + 4 * j) * 4;
    float qv[4][4];
    #pragma unroll
    for (int ci = 0; ci < 4; ++ci) {
      const float2 r0 = st[(j * 4 + ci) * 2];
      const float2 r1 = st[(j * 4 + ci) * 2 + 1];
      const float x1 = r0.x, x3 = r0.y;  // even row: even col, odd col
      const float x2 = r1.x, x4 = r1.y;  // odd  row: even col, odd col
      qv[0][ci] = 0.5f * ((x1 + x2) + (x3 + x4));
      qv[1][ci] = 0.5f * ((x3 + x4) - (x1 + x2));
      qv[2][ci] = 0.5f * ((x2 + x4) - (x1 + x3));
      qv[3][ci] = 0.5f * ((x1 + x4) - (x2 + x3));
    }
    #pragma unroll
    for (int q = 0; q < 4; ++q) {
      ushort4 v = make_ushort4(f2bf(qv[q][0]), f2bf(qv[q][1]), f2bf(qv[q][2]), f2bf(qv[q][3]));
      *(ushort4*)(&lds[ww * SP + q * 64 + c0]) = v;
    }
  }
}

// Phases 2-4 for one row (verbatim R3, incl. internal barriers).
template <bool WBF16>
__device__ __forceinline__ void process_row(unsigned short* lds,
                                            const void* __restrict__ w1p,
                                            const float* __restrict__ b1,
                                            const void* __restrict__ w2p,
                                            const float* __restrict__ b2,
                                            float* __restrict__ out, int n, int hh,
                                            int t, int ww, int cg) {
  const int wv   = t >> 6;        // wave id: o-slice / c4-slice of 64 rows
  const int r    = t & 15;        // MFMA row/col-in-tile
  const int quad = (t & 63) >> 4; // MFMA quad: k-offset (inputs) / row-offset (output)

  // ---------------- Phase 2: GEMM1  D[o][pix] = conv_w . x_dwt;  silu -> lds[pix][o] ----------------
  {
    f32x4 acc[4][4];
    #pragma unroll
    for (int mt = 0; mt < 4; ++mt)
      #pragma unroll
      for (int nt = 0; nt < 4; ++nt)
        acc[mt][nt] = (f32x4){0.0f, 0.0f, 0.0f, 0.0f};

    #pragma unroll
    for (int k0 = 0; k0 < 256; k0 += 32) {
      bf16x8 a[4], b[4];
      #pragma unroll
      for (int mt = 0; mt < 4; ++mt) {  // A: conv_w rows o (L2-resident)
        const int row = wv * 64 + mt * 16 + r;
        if constexpr (WBF16)
          a[mt] = *(const bf16x8*)((const unsigned short*)w1p + row * 256 + quad * 8 + k0);
        else
          a[mt] = ldw8((const float*)w1p + row * 256 + quad * 8 + k0);
      }
      #pragma unroll
      for (int nt = 0; nt < 4; ++nt)   // B: x_dwt[pix][k] (ds_read_b128)
        b[nt] = *(const bf16x8*)(&lds[(nt * 16 + r) * SP + quad * 8 + k0]);
      #pragma unroll
      for (int mt = 0; mt < 4; ++mt)
        #pragma unroll
        for (int nt = 0; nt < 4; ++nt)
          acc[mt][nt] = __builtin_amdgcn_mfma_f32_16x16x32_bf16(a[mt], b[nt], acc[mt][nt], 0, 0, 0);
    }
    __syncthreads();  // all GEMM1 reads of lds done

    // Epilogue: lane holds 4 consecutive o (rows) at col pix -> b64 LDS write
    #pragma unroll
    for (int mt = 0; mt < 4; ++mt) {
      const int ob = wv * 64 + mt * 16 + quad * 4;
      const float4 bb = *(const float4*)(b1 + ob);
      #pragma unroll
      for (int nt = 0; nt < 4; ++nt) {
        const int pix = nt * 16 + r;
        ushort4 v;
        v.x = f2bf(silu(acc[mt][nt][0] + bb.x));
        v.y = f2bf(silu(acc[mt][nt][1] + bb.y));
        v.z = f2bf(silu(acc[mt][nt][2] + bb.z));
        v.w = f2bf(silu(acc[mt][nt][3] + bb.w));
        *(ushort4*)(&lds[pix * SP + ob]) = v;
      }
    }
  }
  __syncthreads();

  // ---------------- Phase 3: GEMM2  D[c4][pix] = conv_out_w . feat -> lds[pix][c4] ----------------
  {
    f32x4 acc[4][4];
    #pragma unroll
    for (int mt = 0; mt < 4; ++mt)
      #pragma unroll
      for (int nt = 0; nt < 4; ++nt)
        acc[mt][nt] = (f32x4){0.0f, 0.0f, 0.0f, 0.0f};

    #pragma unroll
    for (int k0 = 0; k0 < 256; k0 += 32) {
      bf16x8 a[4], b[4];
      #pragma unroll
      for (int mt = 0; mt < 4; ++mt) {  // A: conv_out_w rows c4
        const int row = wv * 64 + mt * 16 + r;
        if constexpr (WBF16)
          a[mt] = *(const bf16x8*)((const unsigned short*)w2p + row * 256 + quad * 8 + k0);
        else
          a[mt] = ldw8((const float*)w2p + row * 256 + quad * 8 + k0);
      }
      #pragma unroll
      for (int nt = 0; nt < 4; ++nt)   // B: feat[pix][o]
        b[nt] = *(const bf16x8*)(&lds[(nt * 16 + r) * SP + quad * 8 + k0]);
      #pragma unroll
      for (int mt = 0; mt < 4; ++mt)
        #pragma unroll
        for (int nt = 0; nt < 4; ++nt)
          acc[mt][nt] = __builtin_amdgcn_mfma_f32_16x16x32_bf16(a[mt], b[nt], acc[mt][nt], 0, 0, 0);
    }
    __syncthreads();  // all GEMM2 reads of lds done

    #pragma unroll
    for (int mt = 0; mt < 4; ++mt) {
      const int cb = wv * 64 + mt * 16 + quad * 4;
      const float4 bb = *(const float4*)(b2 + cb);
      #pragma unroll
      for (int nt = 0; nt < 4; ++nt) {
        const int pix = nt * 16 + r;
        ushort4 v;
        v.x = f2bf(acc[mt][nt][0] + bb.x);
        v.y = f2bf(acc[mt][nt][1] + bb.y);
        v.z = f2bf(acc[mt][nt][2] + bb.z);
        v.w = f2bf(acc[mt][nt][3] + bb.w);
        *(ushort4*)(&lds[pix * SP + cb]) = v;
      }
    }
  }
  __syncthreads();

  // ---------------- Phase 4: IDWT + coalesced float2 stores ----------------
  {
    float* ob_ = out + ((size_t)n * 64 * 128 + (size_t)(2 * hh)) * 128 + 2 * ww;
    #pragma unroll
    for (int j = 0; j < 4; ++j) {
      const int c0 = (cg + 4 * j) * 4;
      unsigned short yb[4][4];
      #pragma unroll
      for (int q = 0; q < 4; ++q) {
        const ushort4 v = *(const ushort4*)(&lds[ww * SP + q * 64 + c0]);
        yb[q][0] = v.x; yb[q][1] = v.y; yb[q][2] = v.z; yb[q][3] = v.w;
      }
      #pragma unroll
      for (int ci = 0; ci < 4; ++ci) {
        const float y1 = 0.5f * bf2f(yb[0][ci]);
        const float y2 = 0.5f * bf2f(yb[1][ci]);
        const float y3 = 0.5f * bf2f(yb[2][ci]);
        const float y4 = 0.5f * bf2f(yb[3][ci]);
        const float s14 = y1 + y4, s23 = y2 + y3;
        const float d14 = y1 - y4, d23 = y2 - y3;
        const float oa  = s14 - s23;  // (2hh,   2ww)
        const float oc  = d14 + d23;  // (2hh,   2ww+1)
        const float obv = d14 - d23;  // (2hh+1, 2ww)
        const float od  = s14 + s23;  // (2hh+1, 2ww+1)
        float* prow = ob_ + (size_t)(c0 + ci) * (128 * 128);
        *(float2*)prow         = make_float2(oa, oc);
        *(float2*)(prow + 128) = make_float2(obv, od);
      }
    }
  }
}

template <bool WBF16>
__global__ __launch_bounds__(256, 2)
void wavelet_fused(const float* __restrict__ x,
                   const void* __restrict__ w1p,
                   const float* __restrict__ b1,
                   const void* __restrict__ w2p,
                   const float* __restrict__ b2,
                   float* __restrict__ out)
{
  // One buffer, three lives per row: x_dwt [pix][c4] -> feat [pix][o] -> y [pix][c4].
  __shared__ unsigned short lds[64 * SP];  // 33,792 B

  const int t  = threadIdx.x;
  const int ww = t & 63;            // pixel column for phases 1/4 (lane-contiguous -> coalesced)
  const int cg = t >> 6;

  const int idx0 = blockIdx.x;            // rows 0..511   (images 0..7)
  const int idx1 = blockIdx.x + 512;      // rows 512..1023 (images 8..15)
  const int n0 = idx0 >> 6, hh0 = idx0 & 63;
  const int n1 = idx1 >> 6, hh1 = idx1 & 63;

  float2 st[32];  // 64-VGPR staging: row i+1's x in flight across row i's GEMMs

  // ---- row 0: load + DWT ----
  load_st(x, n0, hh0, ww, cg, st);
  dwt_write(st, lds, ww, cg);
  __syncthreads();                 // B1: x_dwt(row0) visible

  // issue row 1's loads NOW; consumed after row-0's phases 2-4 (latency fully hidden)
  load_st(x, n1, hh1, ww, cg, st);

  process_row<WBF16>(lds, w1p, b1, w2p, b2, out, n0, hh0, t, ww, cg);

  __syncthreads();                 // B6: phase-4 row-0 LDS reads done before overwrite
  dwt_write(st, lds, ww, cg);      // row-1 DWT into freed buffer
  __syncthreads();                 // B7: x_dwt(row1) visible

  process_row<WBF16>(lds, w1p, b1, w2p, b2, out, n1, hh1, t, ww, cg);
}

extern "C" void kernel_launch(void* const* d_in, const int* in_sizes, int n_in,
                              void* d_out, int out_size, void* d_ws, size_t ws_size,
                              hipStream_t stream) {
  (void)in_sizes; (void)n_in; (void)out_size;
  const float* x  = (const float*)d_in[0];
  const float* w1 = (const float*)d_in[1];
  const float* b1 = (const float*)d_in[2];
  const float* w2 = (const float*)d_in[3];
  const float* b2 = (const float*)d_in[4];
  float* o = (float*)d_out;

  if (ws_size >= 2u * 65536u * sizeof(unsigned short)) {
    unsigned short* wb = (unsigned short*)d_ws;
    cvt_w<<<dim3(64), dim3(256), 0, stream>>>(w1, w2, wb);
    wavelet_fused<true><<<dim3(512), dim3(256), 0, stream>>>(
        x, wb, b1, wb + 65536, b2, o);
  } else {
    wavelet_fused<false><<<dim3(512), dim3(256), 0, stream>>>(
        x, w1, b1, w2, b2, o);
  }
}